// Round 13
// baseline (414.523 us; speedup 1.0000x reference)
//
#include <hip/hip_runtime.h>
#include <hip/hip_bf16.h>

typedef __attribute__((ext_vector_type(8))) short short8;
typedef __attribute__((ext_vector_type(4))) float f32x4;
typedef __attribute__((ext_vector_type(4))) unsigned short ushort4v;

static __device__ __forceinline__ unsigned short f2bf(float f) {
  unsigned u = __float_as_uint(f);
  unsigned r = (u + 0x7fffu + ((u >> 16) & 1u)) >> 16;
  return (unsigned short)r;
}
static __device__ __forceinline__ short8 pack8(float4 a, float4 b) {
  short8 r;
  r[0] = (short)f2bf(a.x); r[1] = (short)f2bf(a.y);
  r[2] = (short)f2bf(a.z); r[3] = (short)f2bf(a.w);
  r[4] = (short)f2bf(b.x); r[5] = (short)f2bf(b.y);
  r[6] = (short)f2bf(b.z); r[7] = (short)f2bf(b.w);
  return r;
}

// DPP-based max over each 16-lane group (all lanes receive the result).
template <int CTRL>
static __device__ __forceinline__ float fmax_dpp(float x) {
  int t = __builtin_amdgcn_update_dpp(__float_as_int(x), __float_as_int(x),
                                      CTRL, 0xF, 0xF, true);
  return fmaxf(x, __int_as_float(t));
}
static __device__ __forceinline__ float max16_dpp(float x) {
  x = fmax_dpp<0xB1>(x);   // quad_perm xor1
  x = fmax_dpp<0x4E>(x);   // quad_perm xor2
  x = fmax_dpp<0x141>(x);  // row_half_mirror
  x = fmax_dpp<0x140>(x);  // row_mirror
  return x;
}

// ---------------------------------------------------------------------------
// 128x128-tile GEMM (unchanged)
// ---------------------------------------------------------------------------
template<int XF32, int OUTF32>
__device__ __forceinline__ void gemm128(
    const void* Xp, const float* W, const float* bias,
    void* outp, float scale, int vt_mode, int bm, int bn)
{
  __shared__ unsigned short Als[128 * 32];
  __shared__ unsigned short Bls[128 * 32];

  const int tid = threadIdx.x;
  const int wave = tid >> 6, lane = tid & 63;
  const int g = lane >> 4, lo = lane & 15;
  const int wr = wave >> 1, wc = wave & 1;
  const int m0 = bm * 128, n0 = bn * 128;

  const f32x4 vzero = {0.f, 0.f, 0.f, 0.f};
  f32x4 acc[4][4];
#pragma unroll
  for (int m = 0; m < 4; ++m)
#pragma unroll
    for (int n = 0; n < 4; ++n) acc[m][n] = vzero;

  const int arow = tid >> 1;
  const int acol = (tid & 1) * 16;
  const float* Af = nullptr;
  const unsigned short* Ab = nullptr;
  if constexpr (XF32) Af = (const float*)Xp + (size_t)(m0 + arow) * 768 + acol;
  else                Ab = (const unsigned short*)Xp + (size_t)(m0 + arow) * 768 + acol;
  const float* Brow = W + (size_t)(n0 + arow) * 768 + acol;

  for (int k0 = 0; k0 < 768; k0 += 32) {
    short8 va0, va1;
    if constexpr (XF32) {
      float4 f0 = *(const float4*)(Af + k0);
      float4 f1 = *(const float4*)(Af + k0 + 4);
      float4 f2 = *(const float4*)(Af + k0 + 8);
      float4 f3 = *(const float4*)(Af + k0 + 12);
      va0 = pack8(f0, f1);
      va1 = pack8(f2, f3);
    } else {
      va0 = *(const short8*)(Ab + k0);
      va1 = *(const short8*)(Ab + k0 + 8);
    }
    float4 g0 = *(const float4*)(Brow + k0);
    float4 g1 = *(const float4*)(Brow + k0 + 4);
    float4 g2 = *(const float4*)(Brow + k0 + 8);
    float4 g3 = *(const float4*)(Brow + k0 + 12);
    short8 vb0 = pack8(g0, g1);
    short8 vb1 = pack8(g2, g3);

    __syncthreads();
    *(short8*)(Als + arow * 32 + acol)     = va0;
    *(short8*)(Als + arow * 32 + acol + 8) = va1;
    *(short8*)(Bls + arow * 32 + acol)     = vb0;
    *(short8*)(Bls + arow * 32 + acol + 8) = vb1;
    __syncthreads();

    short8 af[4], bf[4];
#pragma unroll
    for (int m = 0; m < 4; ++m)
      af[m] = *(const short8*)(Als + (wr * 64 + m * 16 + lo) * 32 + g * 8);
#pragma unroll
    for (int n = 0; n < 4; ++n)
      bf[n] = *(const short8*)(Bls + (wc * 64 + n * 16 + lo) * 32 + g * 8);
#pragma unroll
    for (int m = 0; m < 4; ++m)
#pragma unroll
      for (int n = 0; n < 4; ++n)
        acc[m][n] = __builtin_amdgcn_mfma_f32_16x16x32_bf16(af[m], bf[n], acc[m][n], 0, 0, 0);
  }

#pragma unroll
  for (int n = 0; n < 4; ++n) {
    const int ncol = n0 + wc * 64 + n * 16 + lo;
    const float bb = bias[ncol];
#pragma unroll
    for (int m = 0; m < 4; ++m) {
      const int rowb = m0 + wr * 64 + m * 16 + g * 4;
      if constexpr (OUTF32) {
        float* out = (float*)outp;
#pragma unroll
        for (int r = 0; r < 4; ++r)
          out[(size_t)(rowb + r) * 768 + ncol] = (acc[m][n][r] + bb) * scale;
      } else {
        unsigned short* out = (unsigned short*)outp;
        if (!vt_mode) {
#pragma unroll
          for (int r = 0; r < 4; ++r)
            out[(size_t)(rowb + r) * 768 + ncol] = f2bf((acc[m][n][r] + bb) * scale);
        } else {
          const int b = rowb >> 12, s = rowb & 4095;
          const int hh = ncol >> 6, d = ncol & 63;
          ushort4v pk;
#pragma unroll
          for (int r = 0; r < 4; ++r) pk[r] = f2bf((acc[m][n][r] + bb) * scale);
          *(ushort4v*)(out + (((size_t)b * 12 + hh) * 64 + d) * 4096 + s) = pk;
        }
      }
    }
  }
}

__global__ __launch_bounds__(256, 2) void qkv_proj(
    const float* __restrict__ Qi, const float* __restrict__ Ki,
    const float* __restrict__ Vi,
    const float* __restrict__ Wq, const float* __restrict__ bq,
    const float* __restrict__ Wk, const float* __restrict__ bk,
    const float* __restrict__ Wv, const float* __restrict__ bv,
    unsigned short* __restrict__ qo, unsigned short* __restrict__ ko,
    unsigned short* __restrict__ vto)
{
  const int z = blockIdx.z;
  const float* X = (z == 0) ? Qi : (z == 1) ? Ki : Vi;
  const float* W = (z == 0) ? Wq : (z == 1) ? Wk : Wv;
  const float* bb = (z == 0) ? bq : (z == 1) ? bk : bv;
  unsigned short* out = (z == 0) ? qo : (z == 1) ? ko : vto;
  // q gets 1/sqrt(dk) * log2(e) so softmax runs in exp2 domain
  const float scale = (z == 0) ? 0.18033688011f : 1.0f;
  gemm128<1, 0>(X, W, bb, out, scale, (z == 2) ? 1 : 0, blockIdx.x, blockIdx.y);
}

__global__ __launch_bounds__(256, 2) void out_proj(
    const unsigned short* __restrict__ X, const float* __restrict__ W,
    const float* __restrict__ bias, float* __restrict__ out)
{
  gemm128<0, 1>(X, W, bias, out, 1.0f, 0, blockIdx.x, blockIdx.y);
}

// ---------------------------------------------------------------------------
// Flash attention v7: split-K over KV. 512 thr, 8 waves = 4 row-groups x
// 2 kv-halves. Each wave: 32 q-rows, 32 KV-tiles (its half). K/V fragment
// traffic = r11 level (half of r10) with r8 wave count (latency hiding).
// LDS: K[half] 2x8K @0, V[half] 2x8K @16384, P/wave [32][72] @32768 (68KB).
// Epilogue: position-wise two-accumulator softmax merge via LDS dump.
// (Resubmission of round 12 — container died before measurement.)
// ---------------------------------------------------------------------------
__global__ __launch_bounds__(512, 4) void attn_fwd(
    const unsigned short* qw, const unsigned short* __restrict__ kw,
    const unsigned short* __restrict__ vtw, unsigned short* ow)
{
  __shared__ char LDS[69632];

  const int tid = threadIdx.x, wave = tid >> 6, lane = tid & 63;
  const int g = lane >> 4, lo = lane & 15;
  const int half = wave >> 2, rg = wave & 3;
  const int bh = blockIdx.y, b = bh / 12, hh = bh % 12;
  const int q0 = blockIdx.x * 128 + rg * 32;

  // Q A-fragments: aq[m][s]: rows q0+m*16+lo, k-dims s*32+g*8..+7
  short8 aq[2][2];
#pragma unroll
  for (int m = 0; m < 2; ++m)
#pragma unroll
    for (int s = 0; s < 2; ++s)
      aq[m][s] = *(const short8*)(qw + (size_t)(b * 4096 + q0 + m * 16 + lo) * 768
                                  + hh * 64 + s * 32 + g * 8);

  const f32x4 vzero = {0.f, 0.f, 0.f, 0.f};
  float mx[2][4];
  f32x4 lacc[2];
  f32x4 oacc[2][4];
#pragma unroll
  for (int m = 0; m < 2; ++m) {
    lacc[m] = vzero;
#pragma unroll
    for (int r = 0; r < 4; ++r) mx[m][r] = -1e30f;
#pragma unroll
    for (int n = 0; n < 4; ++n) oacc[m][n] = vzero;
  }

  short8 bone;  // bf16 1.0 B-fragment (row-sum via MFMA)
#pragma unroll
  for (int j = 0; j < 8; ++j) bone[j] = (short)0x3F80;

  // per-lane LDS bases (loop accesses = base + compile-time imm)
  const int rsw = (lo & 7) << 4;
  const int rb0 = lo * 128 + ((g * 16) ^ rsw);
  const int rb1 = lo * 128 + ((64 + g * 16) ^ rsw);
  char* const Kr0 = LDS + half * 8192 + rb0;            // + n*2048
  char* const Kr1 = LDS + half * 8192 + rb1;
  char* const Vr0 = LDS + 16384 + half * 8192 + rb0;    // + nd*2048
  char* const Vr1 = LDS + 16384 + half * 8192 + rb1;
  char* const Pwr = LDS + 32768 + wave * 4608 + (g * 4) * 144 + lo * 2;  // +m*2304+r*144+n*32
  char* const Prd = LDS + 32768 + wave * 4608 + lo * 144 + g * 16;       // +m*2304+{0,64}

  // staging: 512 thr cover 64 rows x 8 chunks; each thread stages BOTH halves
  const int srow = tid >> 3;
  const int sc = tid & 7;
  const unsigned short* krow = kw + ((size_t)b * 4096 + srow) * 768 + hh * 64 + sc * 8;
  const unsigned short* vrow = vtw + ((size_t)bh * 64 + srow) * 4096 + sc * 8;
  const int sdst = srow * 128 + ((sc * 16) ^ ((srow & 7) << 4));
  char* const KsdA = LDS + sdst;            // K half0
  char* const KsdB = LDS + 8192 + sdst;     // K half1
  char* const VsdA = LDS + 16384 + sdst;    // V half0
  char* const VsdB = LDS + 24576 + sdst;    // V half1

  // prefetch tile 0 of each half
  short8 klA = *(const short8*)(krow);
  short8 vlA = *(const short8*)(vrow);
  short8 klB = *(const short8*)(krow + (size_t)2048 * 768);
  short8 vlB = *(const short8*)(vrow + 2048);

  for (int t = 0; t < 32; ++t) {
    // WAR barrier (raw: vmcnt NOT drained -> prefetched loads in flight)
    asm volatile("s_waitcnt lgkmcnt(0)" ::: "memory");
    __builtin_amdgcn_s_barrier();
    *(short8*)KsdA = klA;
    *(short8*)VsdA = vlA;
    *(short8*)KsdB = klB;
    *(short8*)VsdB = vlB;
    {
      const int tn = (t + 1 < 32) ? (t + 1) : 31;  // clamped prefetch
      klA = *(const short8*)(krow + (size_t)(tn * 64) * 768);
      vlA = *(const short8*)(vrow + tn * 64);
      klB = *(const short8*)(krow + (size_t)(2048 + tn * 64) * 768);
      vlB = *(const short8*)(vrow + 2048 + tn * 64);
    }
    asm volatile("s_waitcnt lgkmcnt(0)" ::: "memory");
    __builtin_amdgcn_s_barrier();
    __builtin_amdgcn_sched_barrier(0);

    // ---- per m-half: S = q@k^T, softmax, P write ----
#pragma unroll
    for (int m = 0; m < 2; ++m) {
      f32x4 sa[4];
#pragma unroll
      for (int n = 0; n < 4; ++n) {
        short8 bk0 = *(const short8*)(Kr0 + n * 2048);
        short8 bk1 = *(const short8*)(Kr1 + n * 2048);
        f32x4 tacc = vzero;
        tacc = __builtin_amdgcn_mfma_f32_16x16x32_bf16(aq[m][0], bk0, tacc, 0, 0, 0);
        tacc = __builtin_amdgcn_mfma_f32_16x16x32_bf16(aq[m][1], bk1, tacc, 0, 0, 0);
        sa[n] = tacc;
      }
#pragma unroll
      for (int r = 0; r < 4; ++r) {
        float pm = fmaxf(fmaxf(sa[0][r], sa[1][r]), fmaxf(sa[2][r], sa[3][r]));
        pm = max16_dpp(pm);
        if (pm > mx[m][r] + 8.f) {  // defer-max
          const float fr = __builtin_amdgcn_exp2f(mx[m][r] - pm);
          mx[m][r] = pm;
          lacc[m][r] *= fr;
#pragma unroll
          for (int nd = 0; nd < 4; ++nd) oacc[m][nd][r] *= fr;
        }
#pragma unroll
        for (int n = 0; n < 4; ++n) {
          const float pv = __builtin_amdgcn_exp2f(sa[n][r] - mx[m][r]);
          *(unsigned short*)(Pwr + m * 2304 + r * 144 + n * 32) =
              (unsigned short)(__float_as_uint(pv) >> 16);
        }
      }
    }

    // ---- O += P @ V ; l += P @ 1 (V-frags shared across both m) ----
    short8 ap[2][2];
#pragma unroll
    for (int m = 0; m < 2; ++m) {
      ap[m][0] = *(const short8*)(Prd + m * 2304);
      ap[m][1] = *(const short8*)(Prd + m * 2304 + 64);
    }
#pragma unroll
    for (int nd = 0; nd < 4; ++nd) {
      short8 bv0 = *(const short8*)(Vr0 + nd * 2048);
      short8 bv1 = *(const short8*)(Vr1 + nd * 2048);
#pragma unroll
      for (int m = 0; m < 2; ++m) {
        oacc[m][nd] = __builtin_amdgcn_mfma_f32_16x16x32_bf16(ap[m][0], bv0, oacc[m][nd], 0, 0, 0);
        oacc[m][nd] = __builtin_amdgcn_mfma_f32_16x16x32_bf16(ap[m][1], bv1, oacc[m][nd], 0, 0, 0);
      }
    }
#pragma unroll
    for (int m = 0; m < 2; ++m) {
      lacc[m] = __builtin_amdgcn_mfma_f32_16x16x32_bf16(ap[m][0], bone, lacc[m], 0, 0, 0);
      lacc[m] = __builtin_amdgcn_mfma_f32_16x16x32_bf16(ap[m][1], bone, lacc[m], 0, 0, 0);
    }
  }

  // ---- split-K merge: half1 dumps state; half0 merges position-wise ----
  asm volatile("s_waitcnt lgkmcnt(0)" ::: "memory");
  __builtin_amdgcn_s_barrier();   // all compute reads done; K/V/P LDS free
  char* const mbase = LDS + (size_t)(rg * 64 + lane) * 208;  // 12 float4 used
  if (half == 1) {
    f32x4 mv0 = {mx[0][0], mx[0][1], mx[0][2], mx[0][3]};
    f32x4 mv1 = {mx[1][0], mx[1][1], mx[1][2], mx[1][3]};
    *(f32x4*)(mbase)      = mv0;
    *(f32x4*)(mbase + 16) = mv1;
    *(f32x4*)(mbase + 32) = lacc[0];
    *(f32x4*)(mbase + 48) = lacc[1];
#pragma unroll
    for (int m = 0; m < 2; ++m)
#pragma unroll
      for (int nd = 0; nd < 4; ++nd)
        *(f32x4*)(mbase + 64 + (m * 4 + nd) * 16) = oacc[m][nd];
  }
  asm volatile("s_waitcnt lgkmcnt(0)" ::: "memory");
  __builtin_amdgcn_s_barrier();

  if (half == 0) {
    f32x4 mB0 = *(const f32x4*)(mbase);
    f32x4 mB1 = *(const f32x4*)(mbase + 16);
    f32x4 lB0 = *(const f32x4*)(mbase + 32);
    f32x4 lB1 = *(const f32x4*)(mbase + 48);
#pragma unroll
    for (int m = 0; m < 2; ++m) {
      const f32x4 mBv = m ? mB1 : mB0;
      const f32x4 lBv = m ? lB1 : lB0;
#pragma unroll
      for (int r = 0; r < 4; ++r) {
        const float mA = mx[m][r], mB = mBv[r];
        const float ms = fmaxf(mA, mB);
        const float fA = __builtin_amdgcn_exp2f(mA - ms);
        const float fB = __builtin_amdgcn_exp2f(mB - ms);
        const float lm = lacc[m][r] * fA + lBv[r] * fB;
        const float inv = 1.f / lm;
        const size_t rowoff =
            (size_t)(b * 4096 + q0 + m * 16 + g * 4 + r) * 768 + hh * 64;
#pragma unroll
        for (int nd = 0; nd < 4; ++nd) {
          const float oB = ((const f32x4*)(mbase + 64 + (m * 4 + nd) * 16))[0][r];
          ow[rowoff + nd * 16 + lo] =
              f2bf((oacc[m][nd][r] * fA + oB * fB) * inv);
        }
      }
    }
  }
}

extern "C" void kernel_launch(void* const* d_in, const int* in_sizes, int n_in,
                              void* d_out, int out_size, void* d_ws, size_t ws_size,
                              hipStream_t stream) {
  (void)in_sizes; (void)n_in; (void)out_size; (void)ws_size;
  const float* Qi = (const float*)d_in[0];
  const float* Ki = (const float*)d_in[1];
  const float* Vi = (const float*)d_in[2];
  const float* Wq = (const float*)d_in[3];
  const float* bq = (const float*)d_in[4];
  const float* Wk = (const float*)d_in[5];
  const float* bk = (const float*)d_in[6];
  const float* Wv = (const float*)d_in[7];
  const float* bv = (const float*)d_in[8];
  const float* Wo = (const float*)d_in[9];
  const float* bo = (const float*)d_in[10];

  // ws: q bf16 + v^T bf16 (25.2 MB). k bf16 scratch in d_out's first 12.6 MB
  // (overwritten by out_proj's fp32 output at the end, stream-ordered).
  // Attention output reuses qw in place.
  unsigned short* ws = (unsigned short*)d_ws;
  const size_t NTOK = 8192u * 768u;  // 6291456
  unsigned short* qw  = ws;
  unsigned short* vtw = ws + NTOK;
  unsigned short* kwp = (unsigned short*)d_out;

  qkv_proj<<<dim3(64, 6, 3), 256, 0, stream>>>(Qi, Ki, Vi, Wq, bq, Wk, bk,
                                               Wv, bv, qw, kwp, vtw);
  attn_fwd<<<dim3(32, 24, 1), 512, 0, stream>>>(qw, kwp, vtw, qw);
  out_proj<<<dim3(64, 6, 1), 256, 0, stream>>>(qw, Wo, bo, (float*)d_out);
}

// Round 17
// 346.477 us; speedup vs baseline: 1.1964x; 1.1964x over previous
//
#include <hip/hip_runtime.h>
#include <hip/hip_bf16.h>

typedef __attribute__((ext_vector_type(8))) short short8;
typedef __attribute__((ext_vector_type(4))) float f32x4;
typedef __attribute__((ext_vector_type(4))) unsigned short ushort4v;

static __device__ __forceinline__ unsigned short f2bf(float f) {
  unsigned u = __float_as_uint(f);
  unsigned r = (u + 0x7fffu + ((u >> 16) & 1u)) >> 16;
  return (unsigned short)r;
}
static __device__ __forceinline__ short8 pack8(float4 a, float4 b) {
  short8 r;
  r[0] = (short)f2bf(a.x); r[1] = (short)f2bf(a.y);
  r[2] = (short)f2bf(a.z); r[3] = (short)f2bf(a.w);
  r[4] = (short)f2bf(b.x); r[5] = (short)f2bf(b.y);
  r[6] = (short)f2bf(b.z); r[7] = (short)f2bf(b.w);
  return r;
}

// DPP-based max over each 16-lane group (all lanes receive the result).
template <int CTRL>
static __device__ __forceinline__ float fmax_dpp(float x) {
  int t = __builtin_amdgcn_update_dpp(__float_as_int(x), __float_as_int(x),
                                      CTRL, 0xF, 0xF, true);
  return fmaxf(x, __int_as_float(t));
}
static __device__ __forceinline__ float max16_dpp(float x) {
  x = fmax_dpp<0xB1>(x);   // quad_perm xor1
  x = fmax_dpp<0x4E>(x);   // quad_perm xor2
  x = fmax_dpp<0x141>(x);  // row_half_mirror
  x = fmax_dpp<0x140>(x);  // row_mirror
  return x;
}

// ---------------------------------------------------------------------------
// 128x128-tile GEMM (unchanged from round 8)
// ---------------------------------------------------------------------------
template<int XF32, int OUTF32>
__device__ __forceinline__ void gemm128(
    const void* Xp, const float* W, const float* bias,
    void* outp, float scale, int vt_mode, int bm, int bn)
{
  __shared__ unsigned short Als[128 * 32];
  __shared__ unsigned short Bls[128 * 32];

  const int tid = threadIdx.x;
  const int wave = tid >> 6, lane = tid & 63;
  const int g = lane >> 4, lo = lane & 15;
  const int wr = wave >> 1, wc = wave & 1;
  const int m0 = bm * 128, n0 = bn * 128;

  const f32x4 vzero = {0.f, 0.f, 0.f, 0.f};
  f32x4 acc[4][4];
#pragma unroll
  for (int m = 0; m < 4; ++m)
#pragma unroll
    for (int n = 0; n < 4; ++n) acc[m][n] = vzero;

  const int arow = tid >> 1;
  const int acol = (tid & 1) * 16;
  const float* Af = nullptr;
  const unsigned short* Ab = nullptr;
  if constexpr (XF32) Af = (const float*)Xp + (size_t)(m0 + arow) * 768 + acol;
  else                Ab = (const unsigned short*)Xp + (size_t)(m0 + arow) * 768 + acol;
  const float* Brow = W + (size_t)(n0 + arow) * 768 + acol;

  for (int k0 = 0; k0 < 768; k0 += 32) {
    short8 va0, va1;
    if constexpr (XF32) {
      float4 f0 = *(const float4*)(Af + k0);
      float4 f1 = *(const float4*)(Af + k0 + 4);
      float4 f2 = *(const float4*)(Af + k0 + 8);
      float4 f3 = *(const float4*)(Af + k0 + 12);
      va0 = pack8(f0, f1);
      va1 = pack8(f2, f3);
    } else {
      va0 = *(const short8*)(Ab + k0);
      va1 = *(const short8*)(Ab + k0 + 8);
    }
    float4 g0 = *(const float4*)(Brow + k0);
    float4 g1 = *(const float4*)(Brow + k0 + 4);
    float4 g2 = *(const float4*)(Brow + k0 + 8);
    float4 g3 = *(const float4*)(Brow + k0 + 12);
    short8 vb0 = pack8(g0, g1);
    short8 vb1 = pack8(g2, g3);

    __syncthreads();
    *(short8*)(Als + arow * 32 + acol)     = va0;
    *(short8*)(Als + arow * 32 + acol + 8) = va1;
    *(short8*)(Bls + arow * 32 + acol)     = vb0;
    *(short8*)(Bls + arow * 32 + acol + 8) = vb1;
    __syncthreads();

    short8 af[4], bf[4];
#pragma unroll
    for (int m = 0; m < 4; ++m)
      af[m] = *(const short8*)(Als + (wr * 64 + m * 16 + lo) * 32 + g * 8);
#pragma unroll
    for (int n = 0; n < 4; ++n)
      bf[n] = *(const short8*)(Bls + (wc * 64 + n * 16 + lo) * 32 + g * 8);
#pragma unroll
    for (int m = 0; m < 4; ++m)
#pragma unroll
      for (int n = 0; n < 4; ++n)
        acc[m][n] = __builtin_amdgcn_mfma_f32_16x16x32_bf16(af[m], bf[n], acc[m][n], 0, 0, 0);
  }

#pragma unroll
  for (int n = 0; n < 4; ++n) {
    const int ncol = n0 + wc * 64 + n * 16 + lo;
    const float bb = bias[ncol];
#pragma unroll
    for (int m = 0; m < 4; ++m) {
      const int rowb = m0 + wr * 64 + m * 16 + g * 4;
      if constexpr (OUTF32) {
        float* out = (float*)outp;
#pragma unroll
        for (int r = 0; r < 4; ++r)
          out[(size_t)(rowb + r) * 768 + ncol] = (acc[m][n][r] + bb) * scale;
      } else {
        unsigned short* out = (unsigned short*)outp;
        if (!vt_mode) {
#pragma unroll
          for (int r = 0; r < 4; ++r)
            out[(size_t)(rowb + r) * 768 + ncol] = f2bf((acc[m][n][r] + bb) * scale);
        } else {
          const int b = rowb >> 12, s = rowb & 4095;
          const int hh = ncol >> 6, d = ncol & 63;
          ushort4v pk;
#pragma unroll
          for (int r = 0; r < 4; ++r) pk[r] = f2bf((acc[m][n][r] + bb) * scale);
          *(ushort4v*)(out + (((size_t)b * 12 + hh) * 64 + d) * 4096 + s) = pk;
        }
      }
    }
  }
}

__global__ __launch_bounds__(256, 2) void qkv_proj(
    const float* __restrict__ Qi, const float* __restrict__ Ki,
    const float* __restrict__ Vi,
    const float* __restrict__ Wq, const float* __restrict__ bq,
    const float* __restrict__ Wk, const float* __restrict__ bk,
    const float* __restrict__ Wv, const float* __restrict__ bv,
    unsigned short* __restrict__ qo, unsigned short* __restrict__ ko,
    unsigned short* __restrict__ vto)
{
  const int z = blockIdx.z;
  const float* X = (z == 0) ? Qi : (z == 1) ? Ki : Vi;
  const float* W = (z == 0) ? Wq : (z == 1) ? Wk : Wv;
  const float* bb = (z == 0) ? bq : (z == 1) ? bk : bv;
  unsigned short* out = (z == 0) ? qo : (z == 1) ? ko : vto;
  // q gets 1/sqrt(dk) * log2(e) so softmax runs in exp2 domain
  const float scale = (z == 0) ? 0.18033688011f : 1.0f;
  gemm128<1, 0>(X, W, bb, out, scale, (z == 2) ? 1 : 0, blockIdx.x, blockIdx.y);
}

__global__ __launch_bounds__(256, 2) void out_proj(
    const unsigned short* __restrict__ X, const float* __restrict__ W,
    const float* __restrict__ bias, float* __restrict__ out)
{
  gemm128<0, 1>(X, W, bias, out, 1.0f, 0, blockIdx.x, blockIdx.y);
}

// ---------------------------------------------------------------------------
// Flash attention v10: r11's verified 16x16 structure (32 q-rows/wave,
// 4 waves, grid (32,24)) with two scheduling fixes:
//  (a) K-fragments hoisted out of the m-loop (read ONCE, used by both
//      m-halves) — r11 read them twice; saves 8 ds_read_b128/wave-tile.
//  (b) order: kf-load -> QK-m0 -> [softmax-m0 || QK-m1 (register-fed)]
//      -> softmax-m1 -> P-writes -> PV. QK-m1's MFMAs have no LDS
//      dependency so they overlap softmax-m0's VALU chain (ILP replaces
//      the grid-capped TLP at 12 waves/CU).
// Math/layouts identical to r11 (passed, absmax 1.95e-3).
// LDS: K 8K @0, V 8K @8192, P/wave [32][72] @16384 (34816 B).
// ---------------------------------------------------------------------------
__global__ __launch_bounds__(256, 4) void attn_fwd(
    const unsigned short* qw, const unsigned short* __restrict__ kw,
    const unsigned short* __restrict__ vtw, unsigned short* ow)
{
  __shared__ char LDS[34816];

  const int tid = threadIdx.x, wave = tid >> 6, lane = tid & 63;
  const int g = lane >> 4, lo = lane & 15;
  const int bh = blockIdx.y, b = bh / 12, hh = bh % 12;
  const int q0 = blockIdx.x * 128 + wave * 32;

  // Q A-fragments: aq[m][s]: rows q0+m*16+lo, k-dims s*32+g*8..+7
  short8 aq[2][2];
#pragma unroll
  for (int m = 0; m < 2; ++m)
#pragma unroll
    for (int s = 0; s < 2; ++s)
      aq[m][s] = *(const short8*)(qw + (size_t)(b * 4096 + q0 + m * 16 + lo) * 768
                                  + hh * 64 + s * 32 + g * 8);

  const f32x4 vzero = {0.f, 0.f, 0.f, 0.f};
  float mx[2][4];
  f32x4 lacc[2];
  f32x4 oacc[2][4];
#pragma unroll
  for (int m = 0; m < 2; ++m) {
    lacc[m] = vzero;
#pragma unroll
    for (int r = 0; r < 4; ++r) mx[m][r] = -1e30f;
#pragma unroll
    for (int n = 0; n < 4; ++n) oacc[m][n] = vzero;
  }

  short8 bone;  // bf16 1.0 B-fragment (row-sum via MFMA)
#pragma unroll
  for (int j = 0; j < 8; ++j) bone[j] = (short)0x3F80;

  // per-lane base offsets; all loop accesses are base + compile-time imm
  const int rsw = (lo & 7) << 4;
  const int rb0 = lo * 128 + ((g * 16) ^ rsw);
  const int rb1 = lo * 128 + ((64 + g * 16) ^ rsw);
  char* const Kr0 = LDS + rb0;                  // + n*2048
  char* const Kr1 = LDS + rb1;
  char* const Vr0 = LDS + 8192 + rb0;           // + nd*2048
  char* const Vr1 = LDS + 8192 + rb1;
  // P per wave: [32][72] u16 (144B rows). write: row m*16+g*4+r, col n*16+lo
  char* const Pwr = LDS + 16384 + wave * 4608 + (g * 4) * 144 + lo * 2;  // +m*2304+r*144+n*32
  char* const Prd = LDS + 16384 + wave * 4608 + lo * 144 + g * 16;       // +m*2304+{0,64}

  // staging: 256 threads cover 64 rows x 4 x 32B (2 x 16B chunks each)
  const int srow = tid >> 2;
  const int sc = (tid & 3) * 2;
  const unsigned short* krow = kw + ((size_t)b * 4096 + srow) * 768 + hh * 64 + sc * 8;
  const unsigned short* vrow = vtw + ((size_t)bh * 64 + srow) * 4096 + sc * 8;
  const int sd0 = srow * 128 + ((sc * 16) ^ ((srow & 7) << 4));
  const int sd1 = sd0 ^ 16;  // (sc+1) chunk: sc even -> bit4 flip
  char* const Ksd0 = LDS + sd0;
  char* const Ksd1 = LDS + sd1;
  char* const Vsd0 = LDS + 8192 + sd0;
  char* const Vsd1 = LDS + 8192 + sd1;

  // prefetch tile 0 into regs
  short8 kl0 = *(const short8*)(krow);
  short8 kl1 = *(const short8*)(krow + 8);
  short8 vl0 = *(const short8*)(vrow);
  short8 vl1 = *(const short8*)(vrow + 8);

  for (int kv0 = 0; kv0 < 4096; kv0 += 64) {
    // WAR barrier (raw: vmcnt NOT drained -> prefetched loads stay in flight)
    asm volatile("s_waitcnt lgkmcnt(0)" ::: "memory");
    __builtin_amdgcn_s_barrier();
    *(short8*)Ksd0 = kl0;   // compiler inserts vmcnt wait (data dep)
    *(short8*)Ksd1 = kl1;
    *(short8*)Vsd0 = vl0;
    *(short8*)Vsd1 = vl1;
    if (kv0 + 64 < 4096) {  // prefetch next tile
      kl0 = *(const short8*)(krow + (size_t)(kv0 + 64) * 768);
      kl1 = *(const short8*)(krow + (size_t)(kv0 + 64) * 768 + 8);
      vl0 = *(const short8*)(vrow + kv0 + 64);
      vl1 = *(const short8*)(vrow + kv0 + 64 + 8);
    }
    asm volatile("s_waitcnt lgkmcnt(0)" ::: "memory");
    __builtin_amdgcn_s_barrier();
    __builtin_amdgcn_sched_barrier(0);

    // ---- hoisted K-fragments (read once, used by both m-halves) ----
    short8 kf[4][2];
#pragma unroll
    for (int n = 0; n < 4; ++n) {
      kf[n][0] = *(const short8*)(Kr0 + n * 2048);
      kf[n][1] = *(const short8*)(Kr1 + n * 2048);
    }

    // ---- QK-m0 ----
    f32x4 sa0[4];
#pragma unroll
    for (int n = 0; n < 4; ++n) {
      f32x4 t = vzero;
      t = __builtin_amdgcn_mfma_f32_16x16x32_bf16(aq[0][0], kf[n][0], t, 0, 0, 0);
      t = __builtin_amdgcn_mfma_f32_16x16x32_bf16(aq[0][1], kf[n][1], t, 0, 0, 0);
      sa0[n] = t;
    }

    // ---- QK-m1 (register-fed; overlaps softmax-m0 below via scheduler) ----
    f32x4 sa1[4];
#pragma unroll
    for (int n = 0; n < 4; ++n) {
      f32x4 t = vzero;
      t = __builtin_amdgcn_mfma_f32_16x16x32_bf16(aq[1][0], kf[n][0], t, 0, 0, 0);
      t = __builtin_amdgcn_mfma_f32_16x16x32_bf16(aq[1][1], kf[n][1], t, 0, 0, 0);
      sa1[n] = t;
    }

    // ---- softmax m0 ----
#pragma unroll
    for (int r = 0; r < 4; ++r) {
      float pm = fmaxf(fmaxf(sa0[0][r], sa0[1][r]), fmaxf(sa0[2][r], sa0[3][r]));
      pm = max16_dpp(pm);
      if (pm > mx[0][r] + 8.f) {  // defer-max
        const float fr = __builtin_amdgcn_exp2f(mx[0][r] - pm);
        mx[0][r] = pm;
        lacc[0][r] *= fr;
#pragma unroll
        for (int nd = 0; nd < 4; ++nd) oacc[0][nd][r] *= fr;
      }
#pragma unroll
      for (int n = 0; n < 4; ++n) {
        const float pv = __builtin_amdgcn_exp2f(sa0[n][r] - mx[0][r]);
        *(unsigned short*)(Pwr + r * 144 + n * 32) =
            (unsigned short)(__float_as_uint(pv) >> 16);
      }
    }

    // ---- softmax m1 ----
#pragma unroll
    for (int r = 0; r < 4; ++r) {
      float pm = fmaxf(fmaxf(sa1[0][r], sa1[1][r]), fmaxf(sa1[2][r], sa1[3][r]));
      pm = max16_dpp(pm);
      if (pm > mx[1][r] + 8.f) {
        const float fr = __builtin_amdgcn_exp2f(mx[1][r] - pm);
        mx[1][r] = pm;
        lacc[1][r] *= fr;
#pragma unroll
        for (int nd = 0; nd < 4; ++nd) oacc[1][nd][r] *= fr;
      }
#pragma unroll
      for (int n = 0; n < 4; ++n) {
        const float pv = __builtin_amdgcn_exp2f(sa1[n][r] - mx[1][r]);
        *(unsigned short*)(Pwr + 2304 + r * 144 + n * 32) =
            (unsigned short)(__float_as_uint(pv) >> 16);
      }
    }

    // ---- O += P @ V ; l += P @ 1 (V-frags shared across both m) ----
    short8 ap[2][2];
#pragma unroll
    for (int m = 0; m < 2; ++m) {
      ap[m][0] = *(const short8*)(Prd + m * 2304);
      ap[m][1] = *(const short8*)(Prd + m * 2304 + 64);
    }
#pragma unroll
    for (int nd = 0; nd < 4; ++nd) {
      short8 bv0 = *(const short8*)(Vr0 + nd * 2048);
      short8 bv1 = *(const short8*)(Vr1 + nd * 2048);
#pragma unroll
      for (int m = 0; m < 2; ++m) {
        oacc[m][nd] = __builtin_amdgcn_mfma_f32_16x16x32_bf16(ap[m][0], bv0, oacc[m][nd], 0, 0, 0);
        oacc[m][nd] = __builtin_amdgcn_mfma_f32_16x16x32_bf16(ap[m][1], bv1, oacc[m][nd], 0, 0, 0);
      }
    }
#pragma unroll
    for (int m = 0; m < 2; ++m) {
      lacc[m] = __builtin_amdgcn_mfma_f32_16x16x32_bf16(ap[m][0], bone, lacc[m], 0, 0, 0);
      lacc[m] = __builtin_amdgcn_mfma_f32_16x16x32_bf16(ap[m][1], bone, lacc[m], 0, 0, 0);
    }
  }

  // epilogue: normalize (RNE), store merged-head bf16 [8192][768] (in-place)
#pragma unroll
  for (int m = 0; m < 2; ++m)
#pragma unroll
    for (int r = 0; r < 4; ++r) {
      const float inv = 1.f / lacc[m][r];
      const size_t rowoff =
          (size_t)(b * 4096 + q0 + m * 16 + g * 4 + r) * 768 + hh * 64;
#pragma unroll
      for (int nd = 0; nd < 4; ++nd)
        ow[rowoff + nd * 16 + lo] = f2bf(oacc[m][nd][r] * inv);
    }
}

extern "C" void kernel_launch(void* const* d_in, const int* in_sizes, int n_in,
                              void* d_out, int out_size, void* d_ws, size_t ws_size,
                              hipStream_t stream) {
  (void)in_sizes; (void)n_in; (void)out_size; (void)ws_size;
  const float* Qi = (const float*)d_in[0];
  const float* Ki = (const float*)d_in[1];
  const float* Vi = (const float*)d_in[2];
  const float* Wq = (const float*)d_in[3];
  const float* bq = (const float*)d_in[4];
  const float* Wk = (const float*)d_in[5];
  const float* bk = (const float*)d_in[6];
  const float* Wv = (const float*)d_in[7];
  const float* bv = (const float*)d_in[8];
  const float* Wo = (const float*)d_in[9];
  const float* bo = (const float*)d_in[10];

  // ws: q bf16 + v^T bf16 (25.2 MB). k bf16 scratch in d_out's first 12.6 MB
  // (overwritten by out_proj's fp32 output at the end, stream-ordered).
  // Attention output reuses qw in place.
  unsigned short* ws = (unsigned short*)d_ws;
  const size_t NTOK = 8192u * 768u;  // 6291456
  unsigned short* qw  = ws;
  unsigned short* vtw = ws + NTOK;
  unsigned short* kwp = (unsigned short*)d_out;

  qkv_proj<<<dim3(64, 6, 3), 256, 0, stream>>>(Qi, Ki, Vi, Wq, bq, Wk, bk,
                                               Wv, bv, qw, kwp, vtw);
  attn_fwd<<<dim3(32, 24, 1), 256, 0, stream>>>(qw, kwp, vtw, qw);
  out_proj<<<dim3(64, 6, 1), 256, 0, stream>>>(qw, Wo, bo, (float*)d_out);
}

// Round 18
// 255.273 us; speedup vs baseline: 1.6238x; 1.3573x over previous
//
#include <hip/hip_runtime.h>
#include <hip/hip_bf16.h>

typedef __attribute__((ext_vector_type(8))) short short8;
typedef __attribute__((ext_vector_type(4))) float f32x4;
typedef __attribute__((ext_vector_type(4))) unsigned short ushort4v;

static __device__ __forceinline__ unsigned short f2bf(float f) {
  unsigned u = __float_as_uint(f);
  unsigned r = (u + 0x7fffu + ((u >> 16) & 1u)) >> 16;
  return (unsigned short)r;
}
// library cvt (RNE): compiler can emit v_cvt_pk_bf16_f32 pairs (m240)
static __device__ __forceinline__ unsigned short f2bf_fast(float f) {
  __hip_bfloat16 h = __float2bfloat16(f);
  return *reinterpret_cast<unsigned short*>(&h);
}
static __device__ __forceinline__ short8 pack8(float4 a, float4 b) {
  short8 r;
  r[0] = (short)f2bf_fast(a.x); r[1] = (short)f2bf_fast(a.y);
  r[2] = (short)f2bf_fast(a.z); r[3] = (short)f2bf_fast(a.w);
  r[4] = (short)f2bf_fast(b.x); r[5] = (short)f2bf_fast(b.y);
  r[6] = (short)f2bf_fast(b.z); r[7] = (short)f2bf_fast(b.w);
  return r;
}

// DPP-based max over each 16-lane group (all lanes receive the result).
template <int CTRL>
static __device__ __forceinline__ float fmax_dpp(float x) {
  int t = __builtin_amdgcn_update_dpp(__float_as_int(x), __float_as_int(x),
                                      CTRL, 0xF, 0xF, true);
  return fmaxf(x, __int_as_float(t));
}
static __device__ __forceinline__ float max16_dpp(float x) {
  x = fmax_dpp<0xB1>(x);   // quad_perm xor1
  x = fmax_dpp<0x4E>(x);   // quad_perm xor2
  x = fmax_dpp<0x141>(x);  // row_half_mirror
  x = fmax_dpp<0x140>(x);  // row_mirror
  return x;
}

// ---------------------------------------------------------------------------
// weights fp32 -> bf16 (4 x 768x768). grid (576, 4), 256 thr; 147456 float4/z.
// ---------------------------------------------------------------------------
__global__ __launch_bounds__(256) void cvt_w4(
    const float* __restrict__ w0, const float* __restrict__ w1,
    const float* __restrict__ w2, const float* __restrict__ w3,
    unsigned short* __restrict__ o)
{
  const int z = blockIdx.y;
  const float* src = (z == 0) ? w0 : (z == 1) ? w1 : (z == 2) ? w2 : w3;
  unsigned short* dst = o + (size_t)z * 589824;
  const int i = blockIdx.x * 256 + threadIdx.x;  // exact: 576*256 = 147456
  float4 f = ((const float4*)src)[i];
  ushort4v v;
  v[0] = f2bf_fast(f.x); v[1] = f2bf_fast(f.y);
  v[2] = f2bf_fast(f.z); v[3] = f2bf_fast(f.w);
  ((ushort4v*)dst)[i] = v;
}

// ---------------------------------------------------------------------------
// 128x128-tile GEMM. A: fp32 (XF32=1, converted in regs) or bf16 (XF32=0);
// B (weights): bf16 [out,in] (pre-converted). bias fp32.
// OUTF32=1: fp32 row-major out. OUTF32=0: vt_mode 0 -> bf16 rows,
// vt_mode 1 -> bf16 V^T [b][h][d][s].
// ---------------------------------------------------------------------------
template<int XF32, int OUTF32>
__device__ __forceinline__ void gemm128(
    const void* Xp, const unsigned short* Wb, const float* bias,
    void* outp, float scale, int vt_mode, int bm, int bn)
{
  __shared__ unsigned short Als[128 * 32];
  __shared__ unsigned short Bls[128 * 32];

  const int tid = threadIdx.x;
  const int wave = tid >> 6, lane = tid & 63;
  const int g = lane >> 4, lo = lane & 15;
  const int wr = wave >> 1, wc = wave & 1;
  const int m0 = bm * 128, n0 = bn * 128;

  const f32x4 vzero = {0.f, 0.f, 0.f, 0.f};
  f32x4 acc[4][4];
#pragma unroll
  for (int m = 0; m < 4; ++m)
#pragma unroll
    for (int n = 0; n < 4; ++n) acc[m][n] = vzero;

  const int arow = tid >> 1;        // 0..127
  const int acol = (tid & 1) * 16;  // 0 or 16
  const float* Af = nullptr;
  const unsigned short* Ab = nullptr;
  if constexpr (XF32) Af = (const float*)Xp + (size_t)(m0 + arow) * 768 + acol;
  else                Ab = (const unsigned short*)Xp + (size_t)(m0 + arow) * 768 + acol;
  const unsigned short* Brow = Wb + (size_t)(n0 + arow) * 768 + acol;

  for (int k0 = 0; k0 < 768; k0 += 32) {
    short8 va0, va1;
    if constexpr (XF32) {
      float4 f0 = *(const float4*)(Af + k0);
      float4 f1 = *(const float4*)(Af + k0 + 4);
      float4 f2 = *(const float4*)(Af + k0 + 8);
      float4 f3 = *(const float4*)(Af + k0 + 12);
      va0 = pack8(f0, f1);
      va1 = pack8(f2, f3);
    } else {
      va0 = *(const short8*)(Ab + k0);
      va1 = *(const short8*)(Ab + k0 + 8);
    }
    short8 vb0 = *(const short8*)(Brow + k0);
    short8 vb1 = *(const short8*)(Brow + k0 + 8);

    __syncthreads();  // previous tile fully consumed
    *(short8*)(Als + arow * 32 + acol)     = va0;
    *(short8*)(Als + arow * 32 + acol + 8) = va1;
    *(short8*)(Bls + arow * 32 + acol)     = vb0;
    *(short8*)(Bls + arow * 32 + acol + 8) = vb1;
    __syncthreads();  // tile visible

    short8 af[4], bf[4];
#pragma unroll
    for (int m = 0; m < 4; ++m)
      af[m] = *(const short8*)(Als + (wr * 64 + m * 16 + lo) * 32 + g * 8);
#pragma unroll
    for (int n = 0; n < 4; ++n)
      bf[n] = *(const short8*)(Bls + (wc * 64 + n * 16 + lo) * 32 + g * 8);
#pragma unroll
    for (int m = 0; m < 4; ++m)
#pragma unroll
      for (int n = 0; n < 4; ++n)
        acc[m][n] = __builtin_amdgcn_mfma_f32_16x16x32_bf16(af[m], bf[n], acc[m][n], 0, 0, 0);
  }

#pragma unroll
  for (int n = 0; n < 4; ++n) {
    const int ncol = n0 + wc * 64 + n * 16 + lo;
    const float bb = bias[ncol];
#pragma unroll
    for (int m = 0; m < 4; ++m) {
      const int rowb = m0 + wr * 64 + m * 16 + g * 4;
      if constexpr (OUTF32) {
        float* out = (float*)outp;
#pragma unroll
        for (int r = 0; r < 4; ++r)
          out[(size_t)(rowb + r) * 768 + ncol] = (acc[m][n][r] + bb) * scale;
      } else {
        unsigned short* out = (unsigned short*)outp;
        if (!vt_mode) {
#pragma unroll
          for (int r = 0; r < 4; ++r)
            out[(size_t)(rowb + r) * 768 + ncol] = f2bf((acc[m][n][r] + bb) * scale);
        } else {
          const int b = rowb >> 12, s = rowb & 4095;
          const int hh = ncol >> 6, d = ncol & 63;
          ushort4v pk;
#pragma unroll
          for (int r = 0; r < 4; ++r) pk[r] = f2bf((acc[m][n][r] + bb) * scale);
          *(ushort4v*)(out + (((size_t)b * 12 + hh) * 64 + d) * 4096 + s) = pk;
        }
      }
    }
  }
}

__global__ __launch_bounds__(256, 2) void qkv_proj(
    const float* __restrict__ Qi, const float* __restrict__ Ki,
    const float* __restrict__ Vi,
    const unsigned short* __restrict__ Wq, const float* __restrict__ bq,
    const unsigned short* __restrict__ Wk, const float* __restrict__ bk,
    const unsigned short* __restrict__ Wv, const float* __restrict__ bv,
    unsigned short* __restrict__ qo, unsigned short* __restrict__ ko,
    unsigned short* __restrict__ vto)
{
  const int z = blockIdx.z;
  const float* X = (z == 0) ? Qi : (z == 1) ? Ki : Vi;
  const unsigned short* W = (z == 0) ? Wq : (z == 1) ? Wk : Wv;
  const float* bb = (z == 0) ? bq : (z == 1) ? bk : bv;
  unsigned short* out = (z == 0) ? qo : (z == 1) ? ko : vto;
  // q gets 1/sqrt(dk) * log2(e) so softmax runs in exp2 domain
  const float scale = (z == 0) ? 0.18033688011f : 1.0f;
  gemm128<1, 0>(X, W, bb, out, scale, (z == 2) ? 1 : 0, blockIdx.x, blockIdx.y);
}

__global__ __launch_bounds__(256, 2) void out_proj(
    const unsigned short* __restrict__ X, const unsigned short* __restrict__ W,
    const float* __restrict__ bias, float* __restrict__ out)
{
  gemm128<0, 1>(X, W, bias, out, 1.0f, 0, blockIdx.x, blockIdx.y);
}

// ---------------------------------------------------------------------------
// Flash attention (r8 verbatim — empirical optimum of this family, 200 µs):
// q [8192][768] (pre-scaled by 0.125*log2e, bf16), k bf16, vt [B][H][64][4096]
// bf16. O in-place into qw. grid (32,24), 512 thr (8 waves), 16 q-rows/wave.
// DPP max-reduce, raw v_exp_f32, defer-max THR=8, K/V reg-prefetch with raw
// barriers (vmcnt never drained at barriers), ones-MFMA row-sum, truncating
// d16_hi P store.
// ---------------------------------------------------------------------------
__global__ __launch_bounds__(512, 6) void attn_fwd(
    const unsigned short* qw, const unsigned short* __restrict__ kw,
    const unsigned short* __restrict__ vtw, unsigned short* ow)
{
  __shared__ unsigned short Kls[64 * 64];
  __shared__ unsigned short Vls[64 * 64];
  __shared__ unsigned short Pls[8 * 16 * 72];  // per-wave [16][72]

  const int tid = threadIdx.x, wave = tid >> 6, lane = tid & 63;
  const int g = lane >> 4, lo = lane & 15;
  const int bh = blockIdx.y, b = bh / 12, hh = bh % 12;
  const int q0 = blockIdx.x * 128 + wave * 16;

  // Q A-fragments: rows q0+lo, k-dims s*32+g*8..+7
  short8 aq[2];
#pragma unroll
  for (int s = 0; s < 2; ++s)
    aq[s] = *(const short8*)(qw + (size_t)(b * 4096 + q0 + lo) * 768
                             + hh * 64 + s * 32 + g * 8);

  const f32x4 vzero = {0.f, 0.f, 0.f, 0.f};
  float mx[4];
  f32x4 lacc = vzero;   // row-sum accumulator via ones-MFMA
  f32x4 oacc[4];
#pragma unroll
  for (int r = 0; r < 4; ++r) mx[r] = -1e30f;
#pragma unroll
  for (int n = 0; n < 4; ++n) oacc[n] = vzero;

  short8 bone;  // B-fragment of bf16 1.0 -> D[row][*] = row-sum of A
#pragma unroll
  for (int j = 0; j < 8; ++j) bone[j] = (short)0x3F80;

  unsigned short* Pw = Pls + wave * (16 * 72);
  char* Kb = (char*)Kls;
  char* Vb = (char*)Vls;

  // staging: 512 threads cover 64 rows x 8 x 16B chunks (1 chunk each)
  const int srow = tid >> 3;
  const int sc = tid & 7;
  const unsigned short* krow = kw + ((size_t)b * 4096 + srow) * 768 + hh * 64 + sc * 8;
  const unsigned short* vrow = vtw + ((size_t)bh * 64 + srow) * 4096 + sc * 8;
  const int sdst = srow * 128 + ((sc * 16) ^ ((srow & 7) << 4));

  // prefetch tile 0
  short8 kl = *(const short8*)(krow);
  short8 vl = *(const short8*)(vrow);

  for (int kv0 = 0; kv0 < 4096; kv0 += 64) {
    // WAR: all waves done reading previous tile's LDS. Raw barrier: does NOT
    // drain vmcnt, so the prefetched loads stay in flight.
    asm volatile("s_waitcnt lgkmcnt(0)" ::: "memory");
    __builtin_amdgcn_s_barrier();
    *(short8*)(Kb + sdst) = kl;   // compiler inserts vmcnt wait (data dep)
    *(short8*)(Vb + sdst) = vl;
    if (kv0 + 64 < 4096) {        // prefetch next tile (in flight over compute)
      kl = *(const short8*)(krow + (size_t)(kv0 + 64) * 768);
      vl = *(const short8*)(vrow + (kv0 + 64));
    }
    asm volatile("s_waitcnt lgkmcnt(0)" ::: "memory");  // my writes visible
    __builtin_amdgcn_s_barrier();                       // all writes visible
    __builtin_amdgcn_sched_barrier(0);                  // pin: no hoist above

    // ---- S = q @ k^T (exp2-domain scale folded into q) ----
    f32x4 sa[4];
#pragma unroll
    for (int n = 0; n < 4; ++n) {
      const int row = n * 16 + lo;
      const int rsw = (row & 7) << 4;
      short8 bk0 = *(const short8*)(Kb + row * 128 + ((g * 16) ^ rsw));
      short8 bk1 = *(const short8*)(Kb + row * 128 + ((64 + g * 16) ^ rsw));
      f32x4 t = vzero;
      t = __builtin_amdgcn_mfma_f32_16x16x32_bf16(aq[0], bk0, t, 0, 0, 0);
      t = __builtin_amdgcn_mfma_f32_16x16x32_bf16(aq[1], bk1, t, 0, 0, 0);
      sa[n] = t;
    }

    // ---- online softmax (row = g*4 + r, cols = n*16 + lo) ----
#pragma unroll
    for (int r = 0; r < 4; ++r) {
      float pm = fmaxf(fmaxf(sa[0][r], sa[1][r]), fmaxf(sa[2][r], sa[3][r]));
      pm = max16_dpp(pm);
      if (pm > mx[r] + 8.f) {  // defer-max: rescale only on big max growth
        const float fr = __builtin_amdgcn_exp2f(mx[r] - pm);  // 1st tile: 0
        mx[r] = pm;
        lacc[r] *= fr;
#pragma unroll
        for (int nd = 0; nd < 4; ++nd) oacc[nd][r] *= fr;
      }
#pragma unroll
      for (int n = 0; n < 4; ++n) {
        const float pv = __builtin_amdgcn_exp2f(sa[n][r] - mx[r]);
        // truncating bf16 store: fuses to ds_write_b16_d16_hi (0 VALU rounding)
        *(unsigned short*)((char*)Pw + (g * 4 + r) * 144 + n * 32 + lo * 2) =
            (unsigned short)(__float_as_uint(pv) >> 16);
      }
    }

    // ---- O += P @ V ; l += P @ 1 ----
    short8 ap0 = *(const short8*)((char*)Pw + lo * 144 + g * 16);
    short8 ap1 = *(const short8*)((char*)Pw + lo * 144 + 64 + g * 16);
#pragma unroll
    for (int nd = 0; nd < 4; ++nd) {
      const int row = nd * 16 + lo;
      const int rsw = (row & 7) << 4;
      short8 bv0 = *(const short8*)(Vb + row * 128 + ((g * 16) ^ rsw));
      short8 bv1 = *(const short8*)(Vb + row * 128 + ((64 + g * 16) ^ rsw));
      oacc[nd] = __builtin_amdgcn_mfma_f32_16x16x32_bf16(ap0, bv0, oacc[nd], 0, 0, 0);
      oacc[nd] = __builtin_amdgcn_mfma_f32_16x16x32_bf16(ap1, bv1, oacc[nd], 0, 0, 0);
    }
    lacc = __builtin_amdgcn_mfma_f32_16x16x32_bf16(ap0, bone, lacc, 0, 0, 0);
    lacc = __builtin_amdgcn_mfma_f32_16x16x32_bf16(ap1, bone, lacc, 0, 0, 0);
  }

  // epilogue: normalize (RNE), store merged-head bf16 [8192][768] (in-place ok)
#pragma unroll
  for (int r = 0; r < 4; ++r) {
    const float inv = 1.f / lacc[r];
    const size_t rowoff = (size_t)(b * 4096 + q0 + g * 4 + r) * 768 + hh * 64;
#pragma unroll
    for (int nd = 0; nd < 4; ++nd)
      ow[rowoff + nd * 16 + lo] = f2bf(oacc[nd][r] * inv);
  }
}

extern "C" void kernel_launch(void* const* d_in, const int* in_sizes, int n_in,
                              void* d_out, int out_size, void* d_ws, size_t ws_size,
                              hipStream_t stream) {
  (void)in_sizes; (void)n_in; (void)out_size; (void)ws_size;
  const float* Qi = (const float*)d_in[0];
  const float* Ki = (const float*)d_in[1];
  const float* Vi = (const float*)d_in[2];
  const float* Wq = (const float*)d_in[3];
  const float* bq = (const float*)d_in[4];
  const float* Wk = (const float*)d_in[5];
  const float* bk = (const float*)d_in[6];
  const float* Wv = (const float*)d_in[7];
  const float* bv = (const float*)d_in[8];
  const float* Wo = (const float*)d_in[9];
  const float* bo = (const float*)d_in[10];

  // ws: q bf16 + v^T bf16 (25.2 MB) + 4 bf16 weights (4.7 MB).
  // k bf16 scratch lives in d_out's first 12.6 MB (overwritten by out_proj's
  // fp32 output at the very end, stream-ordered). Attn output in-place in qw.
  unsigned short* ws = (unsigned short*)d_ws;
  const size_t NTOK = 8192u * 768u;  // 6291456
  const size_t NW = 589824;          // 768*768
  unsigned short* qw  = ws;
  unsigned short* vtw = ws + NTOK;
  unsigned short* wbf = ws + 2 * NTOK;
  unsigned short* Wqc = wbf;
  unsigned short* Wkc = wbf + NW;
  unsigned short* Wvc = wbf + 2 * NW;
  unsigned short* Woc = wbf + 3 * NW;
  unsigned short* kwp = (unsigned short*)d_out;

  cvt_w4<<<dim3(576, 4), 256, 0, stream>>>(Wq, Wk, Wv, Wo, wbf);
  qkv_proj<<<dim3(64, 6, 3), 256, 0, stream>>>(Qi, Ki, Vi, Wqc, bq, Wkc, bk,
                                               Wvc, bv, qw, kwp, vtw);
  attn_fwd<<<dim3(32, 24, 1), 512, 0, stream>>>(qw, kwp, vtw, qw);
  out_proj<<<dim3(64, 6, 1), 256, 0, stream>>>(qw, Woc, bo, (float*)d_out);
}